// Round 11
// baseline (6521.355 us; speedup 1.0000x reference)
//
#include <hip/hip_runtime.h>
#include <cstdint>
#include <cstddef>

#define DD 128

typedef float f32x8 __attribute__((ext_vector_type(8)));

// ---------------- CSR build (both graphs in one launch) ----------------

__global__ void count2_k(const int* __restrict__ dstb, const int* __restrict__ dstg,
                         int* __restrict__ degb, int* __restrict__ degg, int E, int gE) {
    int b = blockIdx.x;
    const int* dst = (b < gE) ? dstb : dstg;
    int* deg = (b < gE) ? degb : degg;
    int i = ((b < gE) ? b : b - gE) * blockDim.x + threadIdx.x;
    if (i < E) atomicAdd(&deg[dst[i]], 1);
}

__global__ __launch_bounds__(1024) void scan2_k(const int* __restrict__ degb,
                                                const int* __restrict__ degg,
                                                int* __restrict__ rpb, int* __restrict__ rpg,
                                                int* __restrict__ curb, int* __restrict__ curg,
                                                int n) {
    const int* deg = (blockIdx.x == 0) ? degb : degg;
    int* rp = (blockIdx.x == 0) ? rpb : rpg;
    int* cur = (blockIdx.x == 0) ? curb : curg;
    __shared__ int sums[1024];
    int tid = threadIdx.x;
    int per = (n + 1023) >> 10;
    int start = tid * per;
    int end = min(start + per, n);
    int s = 0;
    for (int i = start; i < end; ++i) s += deg[i];
    sums[tid] = s;
    __syncthreads();
    for (int off = 1; off < 1024; off <<= 1) {
        int v = (tid >= off) ? sums[tid - off] : 0;
        __syncthreads();
        sums[tid] += v;
        __syncthreads();
    }
    int pre = (tid == 0) ? 0 : sums[tid - 1];
    for (int i = start; i < end; ++i) {
        rp[i] = pre;
        cur[i] = pre;
        pre += deg[i];
    }
    if (end == n) rp[n] = pre;
}

__global__ void fill2_k(const int* __restrict__ srcb, const int* __restrict__ dstb,
                        const float* __restrict__ wb,
                        const int* __restrict__ srcg, const int* __restrict__ dstg,
                        const float* __restrict__ wg,
                        int* __restrict__ curb, int* __restrict__ curg,
                        int2* __restrict__ eb, int2* __restrict__ eg, int E, int gE) {
    int b = blockIdx.x;
    bool isb = (b < gE);
    const int* src = isb ? srcb : srcg;
    const int* dst = isb ? dstb : dstg;
    const float* w = isb ? wb : wg;
    int* cur = isb ? curb : curg;
    int2* edges = isb ? eb : eg;
    int i = (isb ? b : b - gE) * blockDim.x + threadIdx.x;
    if (i < E) {
        int d = dst[i];
        int pos = atomicAdd(&cur[d], 1);
        edges[pos] = make_int2(src[i], __float_as_int(w[i]));
    }
}

// ---------------- P = H H^T, S = H + H^T (- I optionally) ----------------

__global__ __launch_bounds__(256) void prep_k(const float* __restrict__ H,
                                              float* __restrict__ P,
                                              float* __restrict__ S, int sub_ident) {
    int idx = blockIdx.x * 256 + threadIdx.x;
    int i = idx >> 7, j = idx & 127;
    float acc = 0.f;
    for (int k = 0; k < DD; ++k) acc += H[i * DD + k] * H[j * DD + k];
    P[idx] = acc;
    float s = H[i * DD + j] + H[j * DD + i];
    if (sub_ident && i == j) s -= 1.0f;
    S[idx] = s;
}

__global__ void aq_k(const float* __restrict__ db, const float* __restrict__ dg,
                     float* __restrict__ aq, int n) {
    int i = blockIdx.x * blockDim.x + threadIdx.x;
    if (i < n) aq[i] = (1.0f / 3.0f) / (db[i] + dg[i] + 1.0f);
}

// ---------------- k1_mix: spmm role (4/5) + denseP role (1/5), zero LDS ----------------
// spmm: AbY = Ab@Y, AgY = Ag@Y  (dual interleaved gather, proven structure)
// denseP: R = X + dg*Y - db*(Y@P1) - dg*(Y@P2)   (depends only on Y -> overlaps gather)

__global__ __launch_bounds__(256, 8) void k1_mix(
    const float* __restrict__ Yc, const float* __restrict__ X,
    const int* __restrict__ rpb, const int2* __restrict__ eb,
    const int* __restrict__ rpg, const int2* __restrict__ eg,
    const float* __restrict__ db, const float* __restrict__ dg,
    const float* __restrict__ P1, const float* __restrict__ P2,
    float* __restrict__ AbY, float* __restrict__ AgY, float* __restrict__ R,
    int n, int ndense)
{
    const int bid = blockIdx.x;
    const int tid = threadIdx.x;
    const int r5 = bid % 5;

    if (r5 != 4) {
        // ---------------- spmm role ----------------
        int sid = (bid / 5) * 4 + r5;
        int node = sid * 4 + (tid >> 6);
        if (node >= n) return;
        int lane = tid & 63;

        int jb = rpb[node], be = rpb[node + 1];
        int jg = rpg[node], ge = rpg[node + 1];
        float b0 = 0.f, b1 = 0.f, g0 = 0.f, g1 = 0.f;

        while (jb + 4 <= be && jg + 4 <= ge) {
            int2 x0 = eb[jb + 0], x1 = eb[jb + 1], x2 = eb[jb + 2], x3 = eb[jb + 3];
            int2 y0 = eg[jg + 0], y1 = eg[jg + 1], y2 = eg[jg + 2], y3 = eg[jg + 3];
            float2 fb0 = *((const float2*)(Yc + (size_t)x0.x * DD) + lane);
            float2 fb1 = *((const float2*)(Yc + (size_t)x1.x * DD) + lane);
            float2 fb2 = *((const float2*)(Yc + (size_t)x2.x * DD) + lane);
            float2 fb3 = *((const float2*)(Yc + (size_t)x3.x * DD) + lane);
            float2 fg0 = *((const float2*)(Yc + (size_t)y0.x * DD) + lane);
            float2 fg1 = *((const float2*)(Yc + (size_t)y1.x * DD) + lane);
            float2 fg2 = *((const float2*)(Yc + (size_t)y2.x * DD) + lane);
            float2 fg3 = *((const float2*)(Yc + (size_t)y3.x * DD) + lane);
            float wb0 = __int_as_float(x0.y), wb1 = __int_as_float(x1.y);
            float wb2 = __int_as_float(x2.y), wb3 = __int_as_float(x3.y);
            float wg0 = __int_as_float(y0.y), wg1 = __int_as_float(y1.y);
            float wg2 = __int_as_float(y2.y), wg3 = __int_as_float(y3.y);
            b0 += wb0 * fb0.x; b1 += wb0 * fb0.y;
            b0 += wb1 * fb1.x; b1 += wb1 * fb1.y;
            b0 += wb2 * fb2.x; b1 += wb2 * fb2.y;
            b0 += wb3 * fb3.x; b1 += wb3 * fb3.y;
            g0 += wg0 * fg0.x; g1 += wg0 * fg0.y;
            g0 += wg1 * fg1.x; g1 += wg1 * fg1.y;
            g0 += wg2 * fg2.x; g1 += wg2 * fg2.y;
            g0 += wg3 * fg3.x; g1 += wg3 * fg3.y;
            jb += 4; jg += 4;
        }
        while (jb + 4 <= be) {
            int2 x0 = eb[jb + 0], x1 = eb[jb + 1], x2 = eb[jb + 2], x3 = eb[jb + 3];
            float2 f0 = *((const float2*)(Yc + (size_t)x0.x * DD) + lane);
            float2 f1 = *((const float2*)(Yc + (size_t)x1.x * DD) + lane);
            float2 f2 = *((const float2*)(Yc + (size_t)x2.x * DD) + lane);
            float2 f3 = *((const float2*)(Yc + (size_t)x3.x * DD) + lane);
            float w0 = __int_as_float(x0.y), w1 = __int_as_float(x1.y);
            float w2 = __int_as_float(x2.y), w3 = __int_as_float(x3.y);
            b0 += w0 * f0.x; b1 += w0 * f0.y;
            b0 += w1 * f1.x; b1 += w1 * f1.y;
            b0 += w2 * f2.x; b1 += w2 * f2.y;
            b0 += w3 * f3.x; b1 += w3 * f3.y;
            jb += 4;
        }
        while (jg + 4 <= ge) {
            int2 y0 = eg[jg + 0], y1 = eg[jg + 1], y2 = eg[jg + 2], y3 = eg[jg + 3];
            float2 f0 = *((const float2*)(Yc + (size_t)y0.x * DD) + lane);
            float2 f1 = *((const float2*)(Yc + (size_t)y1.x * DD) + lane);
            float2 f2 = *((const float2*)(Yc + (size_t)y2.x * DD) + lane);
            float2 f3 = *((const float2*)(Yc + (size_t)y3.x * DD) + lane);
            float w0 = __int_as_float(y0.y), w1 = __int_as_float(y1.y);
            float w2 = __int_as_float(y2.y), w3 = __int_as_float(y3.y);
            g0 += w0 * f0.x; g1 += w0 * f0.y;
            g0 += w1 * f1.x; g1 += w1 * f1.y;
            g0 += w2 * f2.x; g1 += w2 * f2.y;
            g0 += w3 * f3.x; g1 += w3 * f3.y;
            jg += 4;
        }
        for (; jb < be; ++jb) {
            int2 e = eb[jb];
            float2 f = *((const float2*)(Yc + (size_t)e.x * DD) + lane);
            float wv = __int_as_float(e.y);
            b0 += wv * f.x; b1 += wv * f.y;
        }
        for (; jg < ge; ++jg) {
            int2 e = eg[jg];
            float2 f = *((const float2*)(Yc + (size_t)e.x * DD) + lane);
            float wv = __int_as_float(e.y);
            g0 += wv * f.x; g1 += wv * f.y;
        }
        *((float2*)(AbY + (size_t)node * DD) + lane) = make_float2(b0, b1);
        *((float2*)(AgY + (size_t)node * DD) + lane) = make_float2(g0, g1);
        return;
    }

    // ---------------- denseP role ----------------
    int did = bid / 5;
    if (did >= ndense) return;
    const int row0 = (did >> 2) * 64;
    const int cs = did & 3;               // 32-col slice
    const int lane = tid & 63;            // row
    const int w = tid >> 6;               // wave -> 8-col group
    const int cw = cs * 32 + w * 8;
    const int c0 = __builtin_amdgcn_readfirstlane(cw);   // wave-uniform col base
    const int rowc = min(row0 + lane, n - 1);

    const float dbv = db[rowc];
    const float dgv = dg[rowc];
    const float* yrow = Yc + (size_t)rowc * DD;

    float aR[8];
    {
        const float* xp = X + (size_t)rowc * DD + c0;
        const float* yp = yrow + c0;
#pragma unroll
        for (int j = 0; j < 8; ++j) aR[j] = xp[j] + dgv * yp[j];
    }

    const f32x8* pP1 = reinterpret_cast<const f32x8*>(P1 + c0);
    const f32x8* pP2 = reinterpret_cast<const f32x8*>(P2 + c0);
#pragma unroll 2
    for (int kc = 0; kc < 16; ++kc) {
        f32x8 ych = *reinterpret_cast<const f32x8*>(yrow + kc * 8);
#pragma unroll
        for (int t = 0; t < 8; ++t) {
            int k = kc * 8 + t;
            float a = ych[t];
            float am1 = dbv * a;
            float am2 = dgv * a;
            f32x8 r1 = pP1[k * 16];
            f32x8 r2 = pP2[k * 16];
#pragma unroll
            for (int j = 0; j < 8; ++j) aR[j] -= am1 * r1[j] + am2 * r2[j];
        }
    }

    if (row0 + lane < n) {
        float* op = R + (size_t)rowc * DD + c0;
        *reinterpret_cast<float4*>(op) = make_float4(aR[0], aR[1], aR[2], aR[3]);
        *reinterpret_cast<float4*>(op + 4) = make_float4(aR[4], aR[5], aR[6], aR[7]);
    }
}

// ---------------- k2_denseS: Yn = (2/3)Y + aq*(AbY@S1 + AgY@S2m + R), zero LDS ----------------

__global__ __launch_bounds__(256, 8) void k2_denseS(
    const float* __restrict__ Yc,
    const float* __restrict__ AbY, const float* __restrict__ AgY,
    const float* __restrict__ R, const float* __restrict__ aq,
    const float* __restrict__ S1, const float* __restrict__ S2m,
    float* __restrict__ Yn, int n)
{
    const int did = blockIdx.x;
    const int row0 = (did >> 2) * 64;
    const int cs = did & 3;
    const int tid = threadIdx.x;
    const int lane = tid & 63;
    const int w = tid >> 6;
    const int cw = cs * 32 + w * 8;
    const int c0 = __builtin_amdgcn_readfirstlane(cw);
    const int rowc = min(row0 + lane, n - 1);

    const float* brow = AbY + (size_t)rowc * DD;
    const float* grow = AgY + (size_t)rowc * DD;

    float acc[8];
    {
        const float* rp_ = R + (size_t)rowc * DD + c0;
#pragma unroll
        for (int j = 0; j < 8; ++j) acc[j] = rp_[j];
    }

    const f32x8* pS1 = reinterpret_cast<const f32x8*>(S1 + c0);
    const f32x8* pS2 = reinterpret_cast<const f32x8*>(S2m + c0);
#pragma unroll 2
    for (int kc = 0; kc < 16; ++kc) {
        f32x8 bch = *reinterpret_cast<const f32x8*>(brow + kc * 8);
        f32x8 gch = *reinterpret_cast<const f32x8*>(grow + kc * 8);
#pragma unroll
        for (int t = 0; t < 8; ++t) {
            int k = kc * 8 + t;
            float a1 = bch[t];
            float a2 = gch[t];
            f32x8 r1 = pS1[k * 16];
            f32x8 r2 = pS2[k * 16];
#pragma unroll
            for (int j = 0; j < 8; ++j) acc[j] += a1 * r1[j] + a2 * r2[j];
        }
    }

    if (row0 + lane < n) {
        const float aqv = aq[rowc];
        const float* yp = Yc + (size_t)rowc * DD + c0;
        float ov[8];
#pragma unroll
        for (int j = 0; j < 8; ++j)
            ov[j] = (2.0f / 3.0f) * yp[j] + acc[j] * aqv;
        float* op = Yn + (size_t)rowc * DD + c0;
        *reinterpret_cast<float4*>(op) = make_float4(ov[0], ov[1], ov[2], ov[3]);
        *reinterpret_cast<float4*>(op + 4) = make_float4(ov[4], ov[5], ov[6], ov[7]);
    }
}

// ---------------- host ----------------

extern "C" void kernel_launch(void* const* d_in, const int* in_sizes, int n_in,
                              void* d_out, int out_size, void* d_ws, size_t ws_size,
                              hipStream_t stream) {
    const float* X   = (const float*)d_in[0];
    const float* H1  = (const float*)d_in[1];
    const float* H2  = (const float*)d_in[2];
    const float* wb  = (const float*)d_in[3];
    const float* wg  = (const float*)d_in[4];
    const float* db  = (const float*)d_in[5];
    const float* dg  = (const float*)d_in[6];
    const int* srcb  = (const int*)d_in[7];
    const int* dstb  = (const int*)d_in[8];
    const int* srcg  = (const int*)d_in[9];
    const int* dstg  = (const int*)d_in[10];
    const int N = in_sizes[5];
    const int E = in_sizes[3];
    float* Yout = (float*)d_out;

    char* p = (char*)d_ws;
    auto alloc = [&](size_t b) -> void* {
        void* r = (void*)p;
        p += (b + 255) & ~(size_t)255;
        return r;
    };
    float* P1  = (float*)alloc((size_t)DD * DD * 4);
    float* S1  = (float*)alloc((size_t)DD * DD * 4);
    float* P2  = (float*)alloc((size_t)DD * DD * 4);
    float* S2m = (float*)alloc((size_t)DD * DD * 4);
    int* degb = (int*)alloc((size_t)N * 4);
    int* degg = (int*)alloc((size_t)N * 4);
    int* rpb  = (int*)alloc((size_t)(N + 1) * 4);
    int* rpg  = (int*)alloc((size_t)(N + 1) * 4);
    int* curb = (int*)alloc((size_t)N * 4);
    int* curg = (int*)alloc((size_t)N * 4);
    float* aq = (float*)alloc((size_t)N * 4);
    int2* eb  = (int2*)alloc((size_t)E * 8);
    int2* eg  = (int2*)alloc((size_t)E * 8);
    float* AbY = (float*)alloc((size_t)N * DD * 4);
    float* AgY = (float*)alloc((size_t)N * DD * 4);
    float* R   = (float*)alloc((size_t)N * DD * 4);
    float* Yw  = (float*)alloc((size_t)N * DD * 4);

    hipMemsetAsync(degb, 0, (size_t)N * 4, stream);
    hipMemsetAsync(degg, 0, (size_t)N * 4, stream);

    int gE = (E + 255) / 256;
    count2_k<<<2 * gE, 256, 0, stream>>>(dstb, dstg, degb, degg, E, gE);
    scan2_k<<<2, 1024, 0, stream>>>(degb, degg, rpb, rpg, curb, curg, N);
    fill2_k<<<2 * gE, 256, 0, stream>>>(srcb, dstb, wb, srcg, dstg, wg,
                                        curb, curg, eb, eg, E, gE);
    prep_k<<<64, 256, 0, stream>>>(H1, P1, S1, 0);
    prep_k<<<64, 256, 0, stream>>>(H2, P2, S2m, 1);
    aq_k<<<(N + 255) / 256, 256, 0, stream>>>(db, dg, aq, N);

    const float* Ycur = X;
    float* Ybufs[2] = {Yw, Yout};
    int gd = (N + 63) / 64;       // 64-row tiles
    int ND = gd * 4;              // dense col-slice blocks
    int T = 5 * ND;               // k1 grid: 1/5 dense, 4/5 spmm
    for (int s = 0; s < 8; ++s) {
        float* Yn = Ybufs[s & 1];
        k1_mix<<<T, 256, 0, stream>>>(Ycur, X, rpb, eb, rpg, eg, db, dg,
                                      P1, P2, AbY, AgY, R, N, ND);
        k2_denseS<<<ND, 256, 0, stream>>>(Ycur, AbY, AgY, R, aq,
                                          S1, S2m, Yn, N);
        Ycur = Yn;
    }
}

// Round 12
// 3894.917 us; speedup vs baseline: 1.6743x; 1.6743x over previous
//
#include <hip/hip_runtime.h>
#include <cstdint>
#include <cstddef>

#define DD 128
#define ATS2 68    // A-panel row stride: [32 k][64 rows + 4 pad]
#define BQS2 132   // B-panel row stride: [32 k][128 cols + 4 pad]

// ---------------- CSR build (both graphs in one launch) ----------------

__global__ void count2_k(const int* __restrict__ dstb, const int* __restrict__ dstg,
                         int* __restrict__ degb, int* __restrict__ degg, int E, int gE) {
    int b = blockIdx.x;
    const int* dst = (b < gE) ? dstb : dstg;
    int* deg = (b < gE) ? degb : degg;
    int i = ((b < gE) ? b : b - gE) * blockDim.x + threadIdx.x;
    if (i < E) atomicAdd(&deg[dst[i]], 1);
}

__global__ __launch_bounds__(1024) void scan2_k(const int* __restrict__ degb,
                                                const int* __restrict__ degg,
                                                int* __restrict__ rpb, int* __restrict__ rpg,
                                                int* __restrict__ curb, int* __restrict__ curg,
                                                int n) {
    const int* deg = (blockIdx.x == 0) ? degb : degg;
    int* rp = (blockIdx.x == 0) ? rpb : rpg;
    int* cur = (blockIdx.x == 0) ? curb : curg;
    __shared__ int sums[1024];
    int tid = threadIdx.x;
    int per = (n + 1023) >> 10;
    int start = tid * per;
    int end = min(start + per, n);
    int s = 0;
    for (int i = start; i < end; ++i) s += deg[i];
    sums[tid] = s;
    __syncthreads();
    for (int off = 1; off < 1024; off <<= 1) {
        int v = (tid >= off) ? sums[tid - off] : 0;
        __syncthreads();
        sums[tid] += v;
        __syncthreads();
    }
    int pre = (tid == 0) ? 0 : sums[tid - 1];
    for (int i = start; i < end; ++i) {
        rp[i] = pre;
        cur[i] = pre;
        pre += deg[i];
    }
    if (end == n) rp[n] = pre;
}

__global__ void fill2_k(const int* __restrict__ srcb, const int* __restrict__ dstb,
                        const float* __restrict__ wb,
                        const int* __restrict__ srcg, const int* __restrict__ dstg,
                        const float* __restrict__ wg,
                        int* __restrict__ curb, int* __restrict__ curg,
                        int2* __restrict__ eb, int2* __restrict__ eg, int E, int gE) {
    int b = blockIdx.x;
    bool isb = (b < gE);
    const int* src = isb ? srcb : srcg;
    const int* dst = isb ? dstb : dstg;
    const float* w = isb ? wb : wg;
    int* cur = isb ? curb : curg;
    int2* edges = isb ? eb : eg;
    int i = (isb ? b : b - gE) * blockDim.x + threadIdx.x;
    if (i < E) {
        int d = dst[i];
        int pos = atomicAdd(&cur[d], 1);
        edges[pos] = make_int2(src[i], __float_as_int(w[i]));
    }
}

// ---------------- Bcat build: S-slice = H+H^T(-I), P-slice = -(H H^T) ----------------

__global__ __launch_bounds__(256) void prep_k(const float* __restrict__ H,
                                              float* __restrict__ Pdst,   // gets -H H^T
                                              float* __restrict__ Sdst,   // gets H+H^T (-I)
                                              int sub_ident) {
    int idx = blockIdx.x * 256 + threadIdx.x;
    int i = idx >> 7, j = idx & 127;
    float acc = 0.f;
    for (int k = 0; k < DD; ++k) acc += H[i * DD + k] * H[j * DD + k];
    Pdst[idx] = -acc;
    float s = H[i * DD + j] + H[j * DD + i];
    if (sub_ident && i == j) s -= 1.0f;
    Sdst[idx] = s;
}

__global__ void aq_k(const float* __restrict__ db, const float* __restrict__ dg,
                     float* __restrict__ aq, int n) {
    int i = blockIdx.x * blockDim.x + threadIdx.x;
    if (i < n) aq[i] = (1.0f / 3.0f) / (db[i] + dg[i] + 1.0f);
}

// ---------------- spmm2: both graphs, interleaved gather chains (round-7 proven) ----------------

__global__ __launch_bounds__(256, 8) void spmm2_k(
    const int* __restrict__ rpb, const int2* __restrict__ eb,
    const int* __restrict__ rpg, const int2* __restrict__ eg,
    const float* __restrict__ Y,
    float* __restrict__ outb, float* __restrict__ outg, int n)
{
    int node = blockIdx.x * 4 + (threadIdx.x >> 6);
    if (node >= n) return;
    int lane = threadIdx.x & 63;

    int jb = rpb[node], be = rpb[node + 1];
    int jg = rpg[node], ge = rpg[node + 1];
    float b0 = 0.f, b1 = 0.f, g0 = 0.f, g1 = 0.f;

    while (jb + 4 <= be && jg + 4 <= ge) {
        int2 x0 = eb[jb + 0], x1 = eb[jb + 1], x2 = eb[jb + 2], x3 = eb[jb + 3];
        int2 y0 = eg[jg + 0], y1 = eg[jg + 1], y2 = eg[jg + 2], y3 = eg[jg + 3];
        float2 fb0 = *((const float2*)(Y + (size_t)x0.x * DD) + lane);
        float2 fb1 = *((const float2*)(Y + (size_t)x1.x * DD) + lane);
        float2 fb2 = *((const float2*)(Y + (size_t)x2.x * DD) + lane);
        float2 fb3 = *((const float2*)(Y + (size_t)x3.x * DD) + lane);
        float2 fg0 = *((const float2*)(Y + (size_t)y0.x * DD) + lane);
        float2 fg1 = *((const float2*)(Y + (size_t)y1.x * DD) + lane);
        float2 fg2 = *((const float2*)(Y + (size_t)y2.x * DD) + lane);
        float2 fg3 = *((const float2*)(Y + (size_t)y3.x * DD) + lane);
        float wb0 = __int_as_float(x0.y), wb1 = __int_as_float(x1.y);
        float wb2 = __int_as_float(x2.y), wb3 = __int_as_float(x3.y);
        float wg0 = __int_as_float(y0.y), wg1 = __int_as_float(y1.y);
        float wg2 = __int_as_float(y2.y), wg3 = __int_as_float(y3.y);
        b0 += wb0 * fb0.x; b1 += wb0 * fb0.y;
        b0 += wb1 * fb1.x; b1 += wb1 * fb1.y;
        b0 += wb2 * fb2.x; b1 += wb2 * fb2.y;
        b0 += wb3 * fb3.x; b1 += wb3 * fb3.y;
        g0 += wg0 * fg0.x; g1 += wg0 * fg0.y;
        g0 += wg1 * fg1.x; g1 += wg1 * fg1.y;
        g0 += wg2 * fg2.x; g1 += wg2 * fg2.y;
        g0 += wg3 * fg3.x; g1 += wg3 * fg3.y;
        jb += 4; jg += 4;
    }
    while (jb + 4 <= be) {
        int2 x0 = eb[jb + 0], x1 = eb[jb + 1], x2 = eb[jb + 2], x3 = eb[jb + 3];
        float2 f0 = *((const float2*)(Y + (size_t)x0.x * DD) + lane);
        float2 f1 = *((const float2*)(Y + (size_t)x1.x * DD) + lane);
        float2 f2 = *((const float2*)(Y + (size_t)x2.x * DD) + lane);
        float2 f3 = *((const float2*)(Y + (size_t)x3.x * DD) + lane);
        float w0 = __int_as_float(x0.y), w1 = __int_as_float(x1.y);
        float w2 = __int_as_float(x2.y), w3 = __int_as_float(x3.y);
        b0 += w0 * f0.x; b1 += w0 * f0.y;
        b0 += w1 * f1.x; b1 += w1 * f1.y;
        b0 += w2 * f2.x; b1 += w2 * f2.y;
        b0 += w3 * f3.x; b1 += w3 * f3.y;
        jb += 4;
    }
    while (jg + 4 <= ge) {
        int2 y0 = eg[jg + 0], y1 = eg[jg + 1], y2 = eg[jg + 2], y3 = eg[jg + 3];
        float2 f0 = *((const float2*)(Y + (size_t)y0.x * DD) + lane);
        float2 f1 = *((const float2*)(Y + (size_t)y1.x * DD) + lane);
        float2 f2 = *((const float2*)(Y + (size_t)y2.x * DD) + lane);
        float2 f3 = *((const float2*)(Y + (size_t)y3.x * DD) + lane);
        float w0 = __int_as_float(y0.y), w1 = __int_as_float(y1.y);
        float w2 = __int_as_float(y2.y), w3 = __int_as_float(y3.y);
        g0 += w0 * f0.x; g1 += w0 * f0.y;
        g0 += w1 * f1.x; g1 += w1 * f1.y;
        g0 += w2 * f2.x; g1 += w2 * f2.y;
        g0 += w3 * f3.x; g1 += w3 * f3.y;
        jg += 4;
    }
    for (; jb < be; ++jb) {
        int2 e = eb[jb];
        float2 f = *((const float2*)(Y + (size_t)e.x * DD) + lane);
        float wv = __int_as_float(e.y);
        b0 += wv * f.x; b1 += wv * f.y;
    }
    for (; jg < ge; ++jg) {
        int2 e = eg[jg];
        float2 f = *((const float2*)(Y + (size_t)e.x * DD) + lane);
        float wv = __int_as_float(e.y);
        g0 += wv * f.x; g1 += wv * f.y;
    }
    *((float2*)(outb + (size_t)node * DD) + lane) = make_float2(b0, b1);
    *((float2*)(outg + (size_t)node * DD) + lane) = make_float2(g0, g1);
}

// ---------------- denseBig: C = [AbY|AgY|db.Y|dg.Y] @ Bcat  (K=512), fused epilogue ----------------
// Bcat = [S1; S2-I; -P1; -P2].  Yn = (2/3)Y + aq*(C + X + dg*Y)
// 64-row x 128-col tile, 256 threads, 4x8 acc. Panel-streamed A (with row scaling) and B.
// LDS = 8.7KB + 16.9KB = 25.6KB -> 6 blocks/CU (6 waves/SIMD).

__global__ __launch_bounds__(256, 6) void denseBig_k(
    const float* __restrict__ Yc, const float* __restrict__ X,
    const float* __restrict__ AbY, const float* __restrict__ AgY,
    const float* __restrict__ db, const float* __restrict__ dg,
    const float* __restrict__ Bcat, const float* __restrict__ aq,
    float* __restrict__ Yn, int n)
{
    __shared__ float At[32 * ATS2];
    __shared__ float U[32 * BQS2];

    const int tid = threadIdx.x;
    const int cg = tid & 15;    // cols {cg*4..+3} and {64+cg*4..+3}
    const int rg = tid >> 4;    // rows rg*4..+3
    const int row0 = blockIdx.x * 64;

    // staging thread geometry
    const int sr = tid >> 2;              // 0..63 (A-stage row)
    const int sq = (tid & 3) * 8;         // 8-k segment within panel
    const int srow = min(row0 + sr, n - 1);
    const float dbr = db[srow];
    const float dgr = dg[srow];

    const int bkl = tid & 31;             // B-stage k-row in panel
    const int bcb = (tid >> 5) * 16;      // B-stage col base

    float acc[4][8];
#pragma unroll
    for (int i = 0; i < 4; ++i)
#pragma unroll
        for (int j = 0; j < 8; ++j) acc[i][j] = 0.f;

#pragma unroll 1
    for (int p = 0; p < 16; ++p) {
        const int part = p >> 2;          // 0:AbY 1:AgY 2:db*Y 3:dg*Y
        const float* src = (part == 0) ? AbY : (part == 1) ? AgY : Yc;
        const float scale = (part == 0 || part == 1) ? 1.0f : (part == 2 ? dbr : dgr);
        const int kbase = (p & 3) * 32;   // k offset within the 128-col source

        if (p) __syncthreads();           // previous panel fully consumed
        // ---- stage A panel (transposed, scaled) ----
        {
            const float* gp = src + (size_t)srow * DD + kbase + sq;
            float4 v0 = *reinterpret_cast<const float4*>(gp);
            float4 v1 = *reinterpret_cast<const float4*>(gp + 4);
            At[(sq + 0) * ATS2 + sr] = scale * v0.x;
            At[(sq + 1) * ATS2 + sr] = scale * v0.y;
            At[(sq + 2) * ATS2 + sr] = scale * v0.z;
            At[(sq + 3) * ATS2 + sr] = scale * v0.w;
            At[(sq + 4) * ATS2 + sr] = scale * v1.x;
            At[(sq + 5) * ATS2 + sr] = scale * v1.y;
            At[(sq + 6) * ATS2 + sr] = scale * v1.z;
            At[(sq + 7) * ATS2 + sr] = scale * v1.w;
        }
        // ---- stage B panel ----
        {
            const float* gp = Bcat + (size_t)(p * 32 + bkl) * DD + bcb;
            float* bp = U + bkl * BQS2 + bcb;
            *reinterpret_cast<float4*>(bp)      = *reinterpret_cast<const float4*>(gp);
            *reinterpret_cast<float4*>(bp + 4)  = *reinterpret_cast<const float4*>(gp + 4);
            *reinterpret_cast<float4*>(bp + 8)  = *reinterpret_cast<const float4*>(gp + 8);
            *reinterpret_cast<float4*>(bp + 12) = *reinterpret_cast<const float4*>(gp + 12);
        }
        __syncthreads();
        // ---- compute 32 k ----
#pragma unroll 2
        for (int k2 = 0; k2 < 32; ++k2) {
            float4 a  = *reinterpret_cast<const float4*>(&At[k2 * ATS2 + rg * 4]);
            float4 b0 = *reinterpret_cast<const float4*>(&U[k2 * BQS2 + cg * 4]);
            float4 b1 = *reinterpret_cast<const float4*>(&U[k2 * BQS2 + 64 + cg * 4]);
            float av[4] = {a.x, a.y, a.z, a.w};
            float bv[8] = {b0.x, b0.y, b0.z, b0.w, b1.x, b1.y, b1.z, b1.w};
#pragma unroll
            for (int i = 0; i < 4; ++i)
#pragma unroll
                for (int j = 0; j < 8; ++j) acc[i][j] += av[i] * bv[j];
        }
    }

    // ---- epilogue: Yn = (2/3)Y + aq*(acc + X + dg*Y) ----
#pragma unroll
    for (int i = 0; i < 4; ++i) {
        int row = row0 + rg * 4 + i;
        if (row < n) {
            float aqv = aq[row];
            float dgv = dg[row];
#pragma unroll
            for (int hh = 0; hh < 2; ++hh) {
                size_t off = (size_t)row * DD + hh * 64 + cg * 4;
                float4 y = *reinterpret_cast<const float4*>(Yc + off);
                float4 x = *reinterpret_cast<const float4*>(X + off);
                float yv[4] = {y.x, y.y, y.z, y.w};
                float xv[4] = {x.x, x.y, x.z, x.w};
                float ov[4];
#pragma unroll
                for (int q = 0; q < 4; ++q) {
                    int j = hh * 4 + q;
                    ov[q] = (2.0f / 3.0f) * yv[q] + (acc[i][j] + xv[q] + dgv * yv[q]) * aqv;
                }
                *reinterpret_cast<float4*>(Yn + off) = make_float4(ov[0], ov[1], ov[2], ov[3]);
            }
        }
    }
}

// ---------------- host ----------------

extern "C" void kernel_launch(void* const* d_in, const int* in_sizes, int n_in,
                              void* d_out, int out_size, void* d_ws, size_t ws_size,
                              hipStream_t stream) {
    const float* X   = (const float*)d_in[0];
    const float* H1  = (const float*)d_in[1];
    const float* H2  = (const float*)d_in[2];
    const float* wb  = (const float*)d_in[3];
    const float* wg  = (const float*)d_in[4];
    const float* db  = (const float*)d_in[5];
    const float* dg  = (const float*)d_in[6];
    const int* srcb  = (const int*)d_in[7];
    const int* dstb  = (const int*)d_in[8];
    const int* srcg  = (const int*)d_in[9];
    const int* dstg  = (const int*)d_in[10];
    const int N = in_sizes[5];
    const int E = in_sizes[3];
    float* Yout = (float*)d_out;

    char* p = (char*)d_ws;
    auto alloc = [&](size_t b) -> void* {
        void* r = (void*)p;
        p += (b + 255) & ~(size_t)255;
        return r;
    };
    float* Bcat = (float*)alloc((size_t)512 * DD * 4);   // [S1; S2-I; -P1; -P2]
    int* degb = (int*)alloc((size_t)N * 4);
    int* degg = (int*)alloc((size_t)N * 4);
    int* rpb  = (int*)alloc((size_t)(N + 1) * 4);
    int* rpg  = (int*)alloc((size_t)(N + 1) * 4);
    int* curb = (int*)alloc((size_t)N * 4);
    int* curg = (int*)alloc((size_t)N * 4);
    float* aq = (float*)alloc((size_t)N * 4);
    int2* eb  = (int2*)alloc((size_t)E * 8);
    int2* eg  = (int2*)alloc((size_t)E * 8);
    float* AbY = (float*)alloc((size_t)N * DD * 4);
    float* AgY = (float*)alloc((size_t)N * DD * 4);
    float* Yw  = (float*)alloc((size_t)N * DD * 4);

    hipMemsetAsync(degb, 0, (size_t)N * 4, stream);
    hipMemsetAsync(degg, 0, (size_t)N * 4, stream);

    float* S1s  = Bcat;                 // rows 0..127
    float* S2s  = Bcat + 128 * DD;      // rows 128..255
    float* P1s  = Bcat + 256 * DD;      // rows 256..383 (gets -P1)
    float* P2s  = Bcat + 384 * DD;      // rows 384..511 (gets -P2)

    int gE = (E + 255) / 256;
    count2_k<<<2 * gE, 256, 0, stream>>>(dstb, dstg, degb, degg, E, gE);
    scan2_k<<<2, 1024, 0, stream>>>(degb, degg, rpb, rpg, curb, curg, N);
    fill2_k<<<2 * gE, 256, 0, stream>>>(srcb, dstb, wb, srcg, dstg, wg,
                                        curb, curg, eb, eg, E, gE);
    prep_k<<<64, 256, 0, stream>>>(H1, P1s, S1s, 0);
    prep_k<<<64, 256, 0, stream>>>(H2, P2s, S2s, 1);
    aq_k<<<(N + 255) / 256, 256, 0, stream>>>(db, dg, aq, N);

    const float* Ycur = X;
    float* Ybufs[2] = {Yw, Yout};
    int gs = (N + 3) / 4;
    int gd = (N + 63) / 64;
    for (int s = 0; s < 8; ++s) {
        float* Yn = Ybufs[s & 1];
        spmm2_k<<<gs, 256, 0, stream>>>(rpb, eb, rpg, eg, Ycur, AbY, AgY, N);
        denseBig_k<<<gd, 256, 0, stream>>>(Ycur, X, AbY, AgY, db, dg,
                                           Bcat, aq, Yn, N);
        Ycur = Yn;
    }
}